// Round 20
// baseline (46.083 us; speedup 1.0000x reference)
//
#include <hip/hip_runtime.h>
#include <hip/hip_fp16.h>

#define BINS 10

typedef float f32x4 __attribute__((ext_vector_type(4)));  // native vec for nt-load

__device__ __forceinline__ unsigned pk_add_f16x2(unsigned a, unsigned b) {
    __half2 ha = __builtin_bit_cast(__half2, a);
    __half2 hb = __builtin_bit_cast(__half2, b);
    return __builtin_bit_cast(unsigned, __hadd2(ha, hb));   // v_pk_add_f16
}

// ===== ELEM MATH: byte-for-byte from R2/R8/R13/R15 (PASSED absmax 0.0).
// z-form (R3-R7) banned; LDS atomics (R8/R14) banned; volatile RMW (R9)
// banned; fused epilogues (R16-R18) parked; agent-load bypass (R19) dead
// (coherent point IS the L3). Scatter: packed-f16 pairs (R15, passed).
__device__ __forceinline__ void ghm_elem(float x, float tt,
                                         unsigned long long& pk,
                                         unsigned (&acc)[5]) {
    float t = __expf(-fabsf(x));                 // e^{-|x|}
    float u = 1.f + t;
    float r = __builtin_amdgcn_rcpf(u);          // ~1ulp approx, ample slack
    float sig = (x >= 0.f) ? r : t * r;          // sigmoid(x), all ranges
    float d = sig - tt;
    int idx = (int)(fabsf(d) * 10.f);            // trunc (validated R8/R10)
    idx = idx < 9 ? idx : 9;
    pk += 1ull << (6 * idx);                     // packed counts, 6b/bin
    float bce = fmaxf(x, 0.f) - x * tt + __logf(u);  // log1p(e^{-|x|}) = log(u)
    unsigned hv = (unsigned)__builtin_bit_cast(unsigned short, __float2half(bce));
    hv <<= ((idx & 1) << 4);                     // place in low/high half
    const int pair = idx >> 1;
#pragma unroll
    for (int p = 0; p < 5; ++p)                  // cmp + cndmask + pk_add
        acc[p] = pk_add_f16x2(acc[p], (pair == p) ? hv : 0u);
}

#define GHM_QUAD(P, T) do { \
    ghm_elem((P).x, (T).x, pk, acc); \
    ghm_elem((P).y, (T).y, pk, acc); \
    ghm_elem((P).z, (T).z, pk, acc); \
    ghm_elem((P).w, (T).w, pk, acc); } while (0)

#define GHM_FLUSH_ACC do { \
    _Pragma("unroll") \
    for (int p = 0; p < 5; ++p) { \
        __half2 h = __builtin_bit_cast(__half2, acc[p]); \
        s[2 * p]     += __half2float(__low2half(h)); \
        s[2 * p + 1] += __half2float(__high2half(h)); \
        acc[p] = 0u; } } while (0)

// R20 fast path: depth-2 software pipeline (prefetch next pair of quads while
// processing current 8 elems), branch-free steady loop, FLUSH-FREE counts
// (per-thread total elems <= 60 <= 63 at nb=2048 -> one u64 holds all 10
// 6-bit counts, c[10] eliminated, ~10 VGPR saved to stay under the 64 cliff).
__global__ __launch_bounds__(256) void ghm_pass1_fast(
    const float* __restrict__ pred, const float* __restrict__ tgt,
    long long n, int nb,
    float* __restrict__ bsum, int* __restrict__ bcnt)
{
    __shared__ float rsum[4][BINS];
    __shared__ int   rcnt[4][BINS];

    const int tid  = threadIdx.x;
    const int lane = tid & 63;
    const int wave = tid >> 6;

    float s[BINS];
#pragma unroll
    for (int b = 0; b < BINS; ++b) s[b] = 0.f;
    unsigned acc[5];
#pragma unroll
    for (int p = 0; p < 5; ++p) acc[p] = 0u;
    unsigned long long pk = 0;

    const long long n4 = n >> 2;
    const f32x4* p4 = (const f32x4*)pred;
    const f32x4* t4 = (const f32x4*)tgt;

    const long long S  = (long long)nb * 256;    // quad stride
    const long long S2 = S * 2;
    long long ip = (long long)blockIdx.x * 256 + tid;
    int chunk = 0;

    if (ip + S < n4) {
        // prologue: load current pair
        f32x4 cp0 = __builtin_nontemporal_load(&p4[ip]);
        f32x4 ct0 = __builtin_nontemporal_load(&t4[ip]);
        f32x4 cp1 = __builtin_nontemporal_load(&p4[ip + S]);
        f32x4 ct1 = __builtin_nontemporal_load(&t4[ip + S]);
        long long nx = ip + S2;
        while (nx + S < n4) {
            // prefetch next pair BEFORE processing current (depth-2 pipeline)
            f32x4 a0 = __builtin_nontemporal_load(&p4[nx]);
            f32x4 b0 = __builtin_nontemporal_load(&t4[nx]);
            f32x4 a1 = __builtin_nontemporal_load(&p4[nx + S]);
            f32x4 b1 = __builtin_nontemporal_load(&t4[nx + S]);
            GHM_QUAD(cp0, ct0);
            GHM_QUAD(cp1, ct1);
            if (++chunk == 7) { chunk = 0; GHM_FLUSH_ACC; }  // 56-elem window
            cp0 = a0; ct0 = b0; cp1 = a1; ct1 = b1;
            nx += S2;
        }
        GHM_QUAD(cp0, ct0);          // epilogue pair
        GHM_QUAD(cp1, ct1);
        ip = nx;
    }
    for (; ip < n4; ip += S) {       // ragged tail: <=1 quad per thread
        f32x4 p = __builtin_nontemporal_load(&p4[ip]);
        f32x4 t = __builtin_nontemporal_load(&t4[ip]);
        GHM_QUAD(p, t);
    }
    const long long tail0 = n4 << 2; // n%4 scalar remainder: block 0
    if (blockIdx.x == 0 && (long long)tid < (n - tail0))
        ghm_elem(pred[tail0 + tid], tgt[tail0 + tid], pk, acc);
    GHM_FLUSH_ACC;

    // block reduce: shuffle tree per bin; counts unpacked from pk (validated)
#pragma unroll
    for (int b = 0; b < BINS; ++b) {
        float v = s[b];
        int   k = (int)((pk >> (6 * b)) & 63u);
        for (int off = 32; off; off >>= 1) {
            v += __shfl_down(v, off);
            k += __shfl_down(k, off);
        }
        if (lane == 0) { rsum[wave][b] = v; rcnt[wave][b] = k; }
    }
    __syncthreads();
    if (tid < BINS) {
        int b = tid;
        float v = rsum[0][b] + rsum[1][b] + rsum[2][b] + rsum[3][b];
        int   k = rcnt[0][b] + rcnt[1][b] + rcnt[2][b] + rcnt[3][b];
        bsum[(long long)b * nb + blockIdx.x] = v;   // bin-major partials
        bcnt[(long long)b * nb + blockIdx.x] = k;
    }
}

// Safe fallback (R15 verbatim): periodic count flush, used only if per-thread
// element count could exceed 63 (never at n=16e6/nb=2048).
__global__ __launch_bounds__(256) void ghm_pass1_safe(
    const float* __restrict__ pred, const float* __restrict__ tgt,
    long long n, int nb,
    float* __restrict__ bsum, int* __restrict__ bcnt)
{
    __shared__ float rsum[4][BINS];
    __shared__ int   rcnt[4][BINS];
    const int tid  = threadIdx.x;
    const int lane = tid & 63;
    const int wave = tid >> 6;
    float s[BINS];
#pragma unroll
    for (int b = 0; b < BINS; ++b) s[b] = 0.f;
    unsigned acc[5];
#pragma unroll
    for (int p = 0; p < 5; ++p) acc[p] = 0u;
    unsigned long long pk = 0;
    int c[BINS];
#pragma unroll
    for (int b = 0; b < BINS; ++b) c[b] = 0;
    const long long n4 = n >> 2;
    const f32x4* p4 = (const f32x4*)pred;
    const f32x4* t4 = (const f32x4*)tgt;
    const long long stride = (long long)nb * 256;
    int chunk = 0;
    for (long long i = (long long)blockIdx.x * 256 + tid; i < n4; i += stride) {
        f32x4 p = __builtin_nontemporal_load(&p4[i]);
        f32x4 t = __builtin_nontemporal_load(&t4[i]);
        GHM_QUAD(p, t);
        if (++chunk == 14) {
            chunk = 0;
#pragma unroll
            for (int b = 0; b < BINS; ++b) c[b] += (int)((pk >> (6 * b)) & 63u);
            pk = 0;
            GHM_FLUSH_ACC;
        }
    }
    const long long tail0 = n4 << 2;
    if (blockIdx.x == 0 && (long long)tid < (n - tail0))
        ghm_elem(pred[tail0 + tid], tgt[tail0 + tid], pk, acc);
#pragma unroll
    for (int b = 0; b < BINS; ++b) c[b] += (int)((pk >> (6 * b)) & 63u);
    GHM_FLUSH_ACC;
#pragma unroll
    for (int b = 0; b < BINS; ++b) {
        float v = s[b];
        int   k = c[b];
        for (int off = 32; off; off >>= 1) {
            v += __shfl_down(v, off);
            k += __shfl_down(k, off);
        }
        if (lane == 0) { rsum[wave][b] = v; rcnt[wave][b] = k; }
    }
    __syncthreads();
    if (tid < BINS) {
        int b = tid;
        float v = rsum[0][b] + rsum[1][b] + rsum[2][b] + rsum[3][b];
        int   k = rcnt[0][b] + rcnt[1][b] + rcnt[2][b] + rcnt[3][b];
        bsum[(long long)b * nb + blockIdx.x] = v;
        bcnt[(long long)b * nb + blockIdx.x] = k;
    }
}

// 10 waves, one bin per wave. Byte-for-byte validated since R2.
__global__ __launch_bounds__(640) void ghm_pass2(
    const float* __restrict__ bsum, const int* __restrict__ bcnt,
    int nb, float* __restrict__ out)
{
    __shared__ double    ssum[BINS];
    __shared__ long long scnt[BINS];
    const int lane = threadIdx.x & 63;
    const int wave = threadIdx.x >> 6;   // 0..9 == bin

    double    acc = 0.0;
    long long cc  = 0;
    for (int i = lane; i < nb; i += 64) {
        acc += (double)bsum[(long long)wave * nb + i];
        cc  += (long long)bcnt[(long long)wave * nb + i];
    }
    for (int off = 32; off; off >>= 1) {
        acc += __shfl_down(acc, off);
        cc  += __shfl_down(cc, off);
    }
    if (lane == 0) { ssum[wave] = acc; scnt[wave] = cc; }
    __syncthreads();

    if (threadIdx.x == 0) {
        int n = 0;
#pragma unroll
        for (int b = 0; b < BINS; ++b) n += (scnt[b] > 0) ? 1 : 0;
        double loss = 0.0;
        if (n > 0) {
#pragma unroll
            for (int b = 0; b < BINS; ++b)
                if (scnt[b] > 0)
                    loss += ssum[b] / ((double)scnt[b] * (double)n);
        }
        out[0] = (float)loss;
    }
}

extern "C" void kernel_launch(void* const* d_in, const int* in_sizes, int n_in,
                              void* d_out, int out_size, void* d_ws, size_t ws_size,
                              hipStream_t stream) {
    const float* pred = (const float*)d_in[0];
    const float* tgt  = (const float*)d_in[1];
    float* out = (float*)d_out;
    const long long n = (long long)in_sizes[0];

    int nb = 2048;
    const size_t per_block = (size_t)BINS * (sizeof(float) + sizeof(int)); // 80 B
    while (nb > 1 && (size_t)nb * per_block > ws_size) nb >>= 1;

    float* bsum = (float*)d_ws;
    int*   bcnt = (int*)((char*)d_ws + (size_t)nb * BINS * sizeof(float));

    const long long n4 = n >> 2;
    const long long S  = (long long)nb * 256;
    const long long maxElems = 4 * ((n4 + S - 1) / S) + 4;  // per-thread bound

    if (maxElems <= 60)
        ghm_pass1_fast<<<nb, 256, 0, stream>>>(pred, tgt, n, nb, bsum, bcnt);
    else
        ghm_pass1_safe<<<nb, 256, 0, stream>>>(pred, tgt, n, nb, bsum, bcnt);
    ghm_pass2<<<1, 640, 0, stream>>>(bsum, bcnt, nb, out);
}

// Round 21
// 44.684 us; speedup vs baseline: 1.0313x; 1.0313x over previous
//
#include <hip/hip_runtime.h>
#include <hip/hip_fp16.h>

#define BINS 10

typedef float f32x4 __attribute__((ext_vector_type(4)));  // native vec for nt-load

__device__ __forceinline__ unsigned pk_add_f16x2(unsigned a, unsigned b) {
    __half2 ha = __builtin_bit_cast(__half2, a);
    __half2 hb = __builtin_bit_cast(__half2, b);
    return __builtin_bit_cast(unsigned, __hadd2(ha, hb));   // v_pk_add_f16
}

// ===== FINAL (R15 champion, reverted after R16-R20 all failed to beat it).
// ELEM MATH: byte-for-byte from R2/R8 (PASSED absmax 0.0). z-form banned
// (R3-R7 deterministic HW failure). LDS atomics banned (R8/R14: flat-path,
// 101us). Volatile RMW banned (R9: lgkmcnt chain, 50us). Fused epilogues
// parked (R16 wbl2 321us / R17 serial reads 85us / R18 contended atomics
// 91us). Agent-load L3 bypass dead (R19: coherent point IS the L3).
// Explicit SW pipelining null (R20). Scatter: packed-f16 pair accumulators.
__device__ __forceinline__ void ghm_elem(float x, float tt,
                                         unsigned long long& pk,
                                         unsigned (&acc)[5]) {
    float t = __expf(-fabsf(x));                 // e^{-|x|}
    float u = 1.f + t;
    float r = __builtin_amdgcn_rcpf(u);          // ~1ulp approx, ample slack
    float sig = (x >= 0.f) ? r : t * r;          // sigmoid(x), all ranges
    float d = sig - tt;
    int idx = (int)(fabsf(d) * 10.f);            // trunc (validated R8/R10)
    idx = idx < 9 ? idx : 9;
    pk += 1ull << (6 * idx);                     // packed counts, 6b/bin
    float bce = fmaxf(x, 0.f) - x * tt + __logf(u);  // log1p(e^{-|x|}) = log(u)
    unsigned hv = (unsigned)__builtin_bit_cast(unsigned short, __float2half(bce));
    hv <<= ((idx & 1) << 4);                     // place in low/high half
    const int pair = idx >> 1;
#pragma unroll
    for (int p = 0; p < 5; ++p)                  // cmp + cndmask + pk_add
        acc[p] = pk_add_f16x2(acc[p], (pair == p) ? hv : 0u);
}

__global__ __launch_bounds__(256) void ghm_pass1(
    const float* __restrict__ pred, const float* __restrict__ tgt,
    long long n, int nb,
    float* __restrict__ bsum, int* __restrict__ bcnt)
{
    __shared__ float rsum[4][BINS];
    __shared__ int   rcnt[4][BINS];

    const int tid  = threadIdx.x;
    const int lane = tid & 63;
    const int wave = tid >> 6;

    float s[BINS];
#pragma unroll
    for (int b = 0; b < BINS; ++b) s[b] = 0.f;
    unsigned acc[5];
#pragma unroll
    for (int p = 0; p < 5; ++p) acc[p] = 0u;
    unsigned long long pk = 0;
    int c[BINS];
#pragma unroll
    for (int b = 0; b < BINS; ++b) c[b] = 0;

    const long long n4 = n >> 2;
    const f32x4* p4 = (const f32x4*)pred;
    const f32x4* t4 = (const f32x4*)tgt;

    // Chunked contiguous partition + NT loads (R13, proven 51->40us).
    const long long qpb = (n4 + nb - 1) / nb;
    const long long q0  = (long long)blockIdx.x * qpb;
    const long long q1  = (q0 + qpb < n4) ? (q0 + qpb) : n4;

    int chunk = 0;
    for (long long i = q0 + tid; i < q1; i += 512) {   // unroll x2
        f32x4 pa = __builtin_nontemporal_load(&p4[i]);
        f32x4 ta = __builtin_nontemporal_load(&t4[i]);
        const long long j = i + 256;
        f32x4 pb, tb;
        const bool has2 = (j < q1);
        if (has2) {
            pb = __builtin_nontemporal_load(&p4[j]);
            tb = __builtin_nontemporal_load(&t4[j]);
        }
        ghm_elem(pa.x, ta.x, pk, acc);
        ghm_elem(pa.y, ta.y, pk, acc);
        ghm_elem(pa.z, ta.z, pk, acc);
        ghm_elem(pa.w, ta.w, pk, acc);
        if (has2) {
            ghm_elem(pb.x, tb.x, pk, acc);
            ghm_elem(pb.y, tb.y, pk, acc);
            ghm_elem(pb.z, tb.z, pk, acc);
            ghm_elem(pb.w, tb.w, pk, acc);
        }
        if (++chunk == 7) {   // 56 elems: 6-bit count fields <=63, f16 sums <=~320
            chunk = 0;
#pragma unroll
            for (int b = 0; b < BINS; ++b) c[b] += (int)((pk >> (6 * b)) & 63u);
            pk = 0;
#pragma unroll
            for (int p = 0; p < 5; ++p) {
                __half2 h = __builtin_bit_cast(__half2, acc[p]);
                s[2 * p]     += __half2float(__low2half(h));
                s[2 * p + 1] += __half2float(__high2half(h));
                acc[p] = 0u;
            }
        }
    }
    const long long tail0 = n4 << 2;     // n % 4 remainder: block 0
    if (blockIdx.x == 0 && (long long)tid < (n - tail0))
        ghm_elem(pred[tail0 + tid], tgt[tail0 + tid], pk, acc);
#pragma unroll
    for (int b = 0; b < BINS; ++b) c[b] += (int)((pk >> (6 * b)) & 63u);
#pragma unroll
    for (int p = 0; p < 5; ++p) {
        __half2 h = __builtin_bit_cast(__half2, acc[p]);
        s[2 * p]     += __half2float(__low2half(h));
        s[2 * p + 1] += __half2float(__high2half(h));
    }

    // block reduce: shuffle tree per bin, then cross-wave via LDS (validated)
#pragma unroll
    for (int b = 0; b < BINS; ++b) {
        float v = s[b];
        int   k = c[b];
        for (int off = 32; off; off >>= 1) {
            v += __shfl_down(v, off);
            k += __shfl_down(k, off);
        }
        if (lane == 0) { rsum[wave][b] = v; rcnt[wave][b] = k; }
    }
    __syncthreads();
    if (tid < BINS) {
        int b = tid;
        float v = rsum[0][b] + rsum[1][b] + rsum[2][b] + rsum[3][b];
        int   k = rcnt[0][b] + rcnt[1][b] + rcnt[2][b] + rcnt[3][b];
        bsum[(long long)b * nb + blockIdx.x] = v;   // bin-major partials
        bcnt[(long long)b * nb + blockIdx.x] = k;
    }
}

// 10 waves, one bin per wave: parallel strided loads, shuffle reduce.
// Byte-for-byte validated since R2.
__global__ __launch_bounds__(640) void ghm_pass2(
    const float* __restrict__ bsum, const int* __restrict__ bcnt,
    int nb, float* __restrict__ out)
{
    __shared__ double    ssum[BINS];
    __shared__ long long scnt[BINS];
    const int lane = threadIdx.x & 63;
    const int wave = threadIdx.x >> 6;   // 0..9 == bin

    double    acc = 0.0;
    long long cc  = 0;
    for (int i = lane; i < nb; i += 64) {
        acc += (double)bsum[(long long)wave * nb + i];
        cc  += (long long)bcnt[(long long)wave * nb + i];
    }
    for (int off = 32; off; off >>= 1) {
        acc += __shfl_down(acc, off);
        cc  += __shfl_down(cc, off);
    }
    if (lane == 0) { ssum[wave] = acc; scnt[wave] = cc; }
    __syncthreads();

    if (threadIdx.x == 0) {
        int n = 0;
#pragma unroll
        for (int b = 0; b < BINS; ++b) n += (scnt[b] > 0) ? 1 : 0;
        double loss = 0.0;
        if (n > 0) {
#pragma unroll
            for (int b = 0; b < BINS; ++b)
                if (scnt[b] > 0)
                    loss += ssum[b] / ((double)scnt[b] * (double)n);
        }
        out[0] = (float)loss;
    }
}

extern "C" void kernel_launch(void* const* d_in, const int* in_sizes, int n_in,
                              void* d_out, int out_size, void* d_ws, size_t ws_size,
                              hipStream_t stream) {
    const float* pred = (const float*)d_in[0];
    const float* tgt  = (const float*)d_in[1];
    float* out = (float*)d_out;
    const long long n = (long long)in_sizes[0];

    int nb = 2048;
    const size_t per_block = (size_t)BINS * (sizeof(float) + sizeof(int)); // 80 B
    while (nb > 1 && (size_t)nb * per_block > ws_size) nb >>= 1;

    float* bsum = (float*)d_ws;
    int*   bcnt = (int*)((char*)d_ws + (size_t)nb * BINS * sizeof(float));

    ghm_pass1<<<nb, 256, 0, stream>>>(pred, tgt, n, nb, bsum, bcnt);
    ghm_pass2<<<1, 640, 0, stream>>>(bsum, bcnt, nb, out);
}